// Round 9
// baseline (504.957 us; speedup 1.0000x reference)
//
#include <hip/hip_runtime.h>
#include <hip/hip_bf16.h>

// GIN: 2 x (CSR gather-sum + MLP(64->64->64) + BatchNorm + ReLU) + mean pool
// N=50000 nodes, E=800000 edges, H=64, G=16 graphs. fp32 in/out.
// R9: nt-store reverted (R8: +18us, WRITE 51->59MB — nt makes 4B scatters
// full HBM partial-line writes). CSR placement now two-pass: bucket partition
// (782 dst-buckets, sequential-in-time cursor claims -> full-line writes of
// 8B pairs) then per-bucket block-local scatter into a 4KB csr window.

constexpr int NN = 50000;
constexpr int NE = 800000;
constexpr int HD = 64;
constexpr int NG = 16;
constexpr float BN_EPS = 1e-5f;
constexpr int SCAN_BLOCKS = (NN + 255) / 256;  // 196
constexpr int NBUCK = (NN + 63) / 64;          // 782 buckets of 64 rows

// ---------------------------------------------------------------------------
// CSR build: degree histogram -> exclusive scan -> bucket partition -> place.
// ---------------------------------------------------------------------------
__global__ __launch_bounds__(256)
void count_kernel(const int* __restrict__ ei, int* __restrict__ cnt) {
    int e = blockIdx.x * 256 + threadIdx.x;
    if (e >= NE) return;
    atomicAdd(&cnt[ei[NE + e]], 1);
}

__global__ __launch_bounds__(256)
void scan1_kernel(const int* __restrict__ cnt, int* __restrict__ row_ptr,
                  int* __restrict__ partials) {
    int i = blockIdx.x * 256 + threadIdx.x;
    int v = (i < NN) ? cnt[i] : 0;
    __shared__ int s[256];
    s[threadIdx.x] = v;
    __syncthreads();
#pragma unroll
    for (int off = 1; off < 256; off <<= 1) {
        int add = (threadIdx.x >= off) ? s[threadIdx.x - off] : 0;
        __syncthreads();
        s[threadIdx.x] += add;
        __syncthreads();
    }
    if (i < NN) row_ptr[i] = s[threadIdx.x] - v;  // exclusive
    if (threadIdx.x == 255) partials[blockIdx.x] = s[255];
}

__global__ __launch_bounds__(256)
void scan2_kernel(int* __restrict__ partials, int* __restrict__ poffs) {
    int v = (threadIdx.x < SCAN_BLOCKS) ? partials[threadIdx.x] : 0;
    __shared__ int s[256];
    s[threadIdx.x] = v;
    __syncthreads();
#pragma unroll
    for (int off = 1; off < 256; off <<= 1) {
        int add = (threadIdx.x >= off) ? s[threadIdx.x - off] : 0;
        __syncthreads();
        s[threadIdx.x] += add;
        __syncthreads();
    }
    poffs[threadIdx.x] = s[threadIdx.x] - v;  // exclusive
}

__global__ __launch_bounds__(256)
void scan3_kernel(int* __restrict__ row_ptr, const int* __restrict__ poffs,
                  int* __restrict__ cursor, int* __restrict__ bcur) {
    int i = blockIdx.x * 256 + threadIdx.x;
    if (i < NN) {
        int v = row_ptr[i] + poffs[blockIdx.x];
        row_ptr[i] = v;
        cursor[i] = v;
        if ((i & 63) == 0) bcur[i >> 6] = v;  // bucket cursor = row_ptr[b*64]
    }
    if (i == 0) row_ptr[NN] = NE;
}

// Pass 1: scatter (src,dst) into dst-buckets. Cursor claims are sequential in
// time per bucket -> part[] lines fill completely before eviction.
__global__ __launch_bounds__(256)
void partition_kernel(const int* __restrict__ ei, int* __restrict__ bcur,
                      int2* __restrict__ part) {
    int e = blockIdx.x * 256 + threadIdx.x;
    if (e >= NE) return;
    int src = ei[e];
    int dst = ei[NE + e];
    int pos = atomicAdd(&bcur[dst >> 6], 1);
    part[pos] = make_int2(src, dst);
}

// Pass 2: one block per bucket; contiguous reads of part, scatter confined to
// the bucket's ~4KB csr window (block-local -> full-line writes).
__global__ __launch_bounds__(256)
void place2_kernel(const int2* __restrict__ part, const int* __restrict__ row_ptr,
                   int* __restrict__ cursor, int* __restrict__ csr) {
    int b = blockIdx.x;
    int s = row_ptr[b << 6];
    int e = row_ptr[min((b + 1) << 6, NN)];
    for (int i = s + threadIdx.x; i < e; i += 256) {
        int2 p = part[i];
        int pos = atomicAdd(&cursor[p.y], 1);
        csr[pos] = p.x;
    }
}

// ---------------------------------------------------------------------------
// fp32 -> bf16 table conversion. Also zeroes cnt[] for the following
// count_kernel (stream order guarantees completion first).
// ---------------------------------------------------------------------------
__global__ __launch_bounds__(256)
void x2bf_kernel(const float* __restrict__ x, __hip_bfloat16* __restrict__ xb,
                 int* __restrict__ cnt) {
    int i4 = blockIdx.x * 256 + threadIdx.x;
    if (i4 < NN) cnt[i4] = 0;
    if (i4 >= NN * HD / 4) return;
    float4 v = *(const float4*)(x + (size_t)i4 * 4);
    union { ushort4 u; __hip_bfloat16 b[4]; } p;
    p.b[0] = __float2bfloat16(v.x);
    p.b[1] = __float2bfloat16(v.y);
    p.b[2] = __float2bfloat16(v.z);
    p.b[3] = __float2bfloat16(v.w);
    *(ushort4*)((unsigned short*)xb + (size_t)i4 * 4) = p.u;
}

// ---------------------------------------------------------------------------
// Aggregation: one wave per dst row. h[r] = x_f32[r] + sum_nb bf16(x)[nb].
// Gather pipeline 8 deep. Block 0 zeroes stats for the following mlp_kernel.
// ---------------------------------------------------------------------------
__global__ __launch_bounds__(256)
void agg_kernel(const float* __restrict__ x, const __hip_bfloat16* __restrict__ xb,
                const int* __restrict__ row_ptr, const int* __restrict__ csr,
                float* __restrict__ h, float* __restrict__ stats) {
    if (blockIdx.x == 0 && threadIdx.x < 128) stats[threadIdx.x] = 0.f;
    int row = blockIdx.x * 4 + (threadIdx.x >> 6);
    int lane = threadIdx.x & 63;
    int s = row_ptr[row], e = row_ptr[row + 1];
    int cnt = e - s;
    int ids = (lane < cnt) ? csr[s + lane] : 0;
    float acc = x[(size_t)row * HD + lane];
    int m = min(cnt, 64);
    int j = 0;
    float a0 = 0.f, a1 = 0.f, a2 = 0.f, a3 = 0.f;
    float a4 = 0.f, a5 = 0.f, a6 = 0.f, a7 = 0.f;
    for (; j + 8 <= m; j += 8) {
        int nb0 = __shfl(ids, j);
        int nb1 = __shfl(ids, j + 1);
        int nb2 = __shfl(ids, j + 2);
        int nb3 = __shfl(ids, j + 3);
        int nb4 = __shfl(ids, j + 4);
        int nb5 = __shfl(ids, j + 5);
        int nb6 = __shfl(ids, j + 6);
        int nb7 = __shfl(ids, j + 7);
        float v0 = __bfloat162float(xb[(size_t)nb0 * HD + lane]);
        float v1 = __bfloat162float(xb[(size_t)nb1 * HD + lane]);
        float v2 = __bfloat162float(xb[(size_t)nb2 * HD + lane]);
        float v3 = __bfloat162float(xb[(size_t)nb3 * HD + lane]);
        float v4 = __bfloat162float(xb[(size_t)nb4 * HD + lane]);
        float v5 = __bfloat162float(xb[(size_t)nb5 * HD + lane]);
        float v6 = __bfloat162float(xb[(size_t)nb6 * HD + lane]);
        float v7 = __bfloat162float(xb[(size_t)nb7 * HD + lane]);
        a0 += v0; a1 += v1; a2 += v2; a3 += v3;
        a4 += v4; a5 += v5; a6 += v6; a7 += v7;
    }
    acc += ((a0 + a1) + (a2 + a3)) + ((a4 + a5) + (a6 + a7));
    for (; j < m; j++) {
        int nb = __shfl(ids, j);
        acc += __bfloat162float(xb[(size_t)nb * HD + lane]);
    }
    for (int jj = s + 64; jj < e; jj++) {  // degree > 64 fallback
        acc += __bfloat162float(xb[(size_t)csr[jj] * HD + lane]);
    }
    h[(size_t)row * HD + lane] = acc;
}

// ---------------------------------------------------------------------------
// Fused MLP + BN-stats epilogue. hout = ReLU(hin @ W1 + b1) @ W2 + b2.
// Block = 128 rows x 256 threads; wave wv owns cols [wv*16,+16); thread does
// rows lane and lane+64. One LDS tile reused input->t->output (barriered).
// Block 0 zeroes psums (only touched by pool kernels, 2 dispatches later).
// ---------------------------------------------------------------------------
__global__ __launch_bounds__(256)
void mlp_kernel(const float* __restrict__ hin, float* __restrict__ hout,
                const float* __restrict__ W1, const float* __restrict__ b1,
                const float* __restrict__ W2, const float* __restrict__ b2,
                float* __restrict__ stats, float* __restrict__ psums) {
    __shared__ float sh[128 * 65];
    __shared__ float sW[64 * 64];
    __shared__ float sb[64];
    __shared__ float red[2][4][64];
    int tid = threadIdx.x;
    int base = blockIdx.x * 128;

    if (blockIdx.x == 0) {
        float4 z = make_float4(0.f, 0.f, 0.f, 0.f);
        *(float4*)(psums + tid * 4) = z;
    }
    for (int i = tid; i < 4096; i += 256) sW[i] = W1[i];
    if (tid < 64) sb[tid] = b1[tid];
#pragma unroll
    for (int i = 0; i < 8; i++) {
        int i4 = tid + 256 * i;          // 0..2047 float4s
        int row = i4 >> 4, col = (i4 & 15) * 4;
        int grow = base + row;
        float4 v = (grow < NN) ? *(const float4*)(hin + (size_t)grow * HD + col)
                               : make_float4(0.f, 0.f, 0.f, 0.f);
        float* d = sh + row * 65 + col;
        d[0] = v.x; d[1] = v.y; d[2] = v.z; d[3] = v.w;
    }
    __syncthreads();

    int wv = tid >> 6;
    int lane = tid & 63;

    float acc0[16], acc1[16];
    // ---- GEMM1 ----
#pragma unroll
    for (int j = 0; j < 16; j++) { acc0[j] = sb[wv * 16 + j]; acc1[j] = acc0[j]; }
    for (int k = 0; k < 64; k++) {
        float a0 = sh[lane * 65 + k];
        float a1 = sh[(64 + lane) * 65 + k];
        const float4* wr = (const float4*)(sW + k * 64 + wv * 16);
#pragma unroll
        for (int q = 0; q < 4; q++) {
            float4 w = wr[q];
            acc0[4 * q + 0] = fmaf(a0, w.x, acc0[4 * q + 0]);
            acc0[4 * q + 1] = fmaf(a0, w.y, acc0[4 * q + 1]);
            acc0[4 * q + 2] = fmaf(a0, w.z, acc0[4 * q + 2]);
            acc0[4 * q + 3] = fmaf(a0, w.w, acc0[4 * q + 3]);
            acc1[4 * q + 0] = fmaf(a1, w.x, acc1[4 * q + 0]);
            acc1[4 * q + 1] = fmaf(a1, w.y, acc1[4 * q + 1]);
            acc1[4 * q + 2] = fmaf(a1, w.z, acc1[4 * q + 2]);
            acc1[4 * q + 3] = fmaf(a1, w.w, acc1[4 * q + 3]);
        }
    }
    __syncthreads();  // all input reads of sh + W1 reads of sW complete

    // t = ReLU(acc) overwrites sh; restage W2/b2
#pragma unroll
    for (int j = 0; j < 16; j++) {
        sh[lane * 65 + wv * 16 + j] = fmaxf(acc0[j], 0.f);
        sh[(64 + lane) * 65 + wv * 16 + j] = fmaxf(acc1[j], 0.f);
    }
    for (int i = tid; i < 4096; i += 256) sW[i] = W2[i];
    if (tid < 64) sb[tid] = b2[tid];
    __syncthreads();

    // ---- GEMM2 ----
#pragma unroll
    for (int j = 0; j < 16; j++) { acc0[j] = sb[wv * 16 + j]; acc1[j] = acc0[j]; }
    for (int k = 0; k < 64; k++) {
        float a0 = sh[lane * 65 + k];
        float a1 = sh[(64 + lane) * 65 + k];
        const float4* wr = (const float4*)(sW + k * 64 + wv * 16);
#pragma unroll
        for (int q = 0; q < 4; q++) {
            float4 w = wr[q];
            acc0[4 * q + 0] = fmaf(a0, w.x, acc0[4 * q + 0]);
            acc0[4 * q + 1] = fmaf(a0, w.y, acc0[4 * q + 1]);
            acc0[4 * q + 2] = fmaf(a0, w.z, acc0[4 * q + 2]);
            acc0[4 * q + 3] = fmaf(a0, w.w, acc0[4 * q + 3]);
            acc1[4 * q + 0] = fmaf(a1, w.x, acc1[4 * q + 0]);
            acc1[4 * q + 1] = fmaf(a1, w.y, acc1[4 * q + 1]);
            acc1[4 * q + 2] = fmaf(a1, w.z, acc1[4 * q + 2]);
            acc1[4 * q + 3] = fmaf(a1, w.w, acc1[4 * q + 3]);
        }
    }
    __syncthreads();  // all t reads complete before overwrite
#pragma unroll
    for (int j = 0; j < 16; j++) {
        sh[lane * 65 + wv * 16 + j] = acc0[j];
        sh[(64 + lane) * 65 + wv * 16 + j] = acc1[j];
    }
    __syncthreads();

    // coalesced store (float4)
#pragma unroll
    for (int i = 0; i < 8; i++) {
        int i4 = tid + 256 * i;
        int row = i4 >> 4, col = (i4 & 15) * 4;
        int grow = base + row;
        if (grow < NN) {
            const float* s = sh + row * 65 + col;
            *(float4*)(hout + (size_t)grow * HD + col) =
                make_float4(s[0], s[1], s[2], s[3]);
        }
    }

    // ---- fused BN-stats partials over the output tile ----
    {
        int col = tid & 63;
        int r0 = (tid >> 6) * 32;
        float s = 0.f, ss = 0.f;
#pragma unroll
        for (int r = 0; r < 32; r++) {
            float v = (base + r0 + r < NN) ? sh[(r0 + r) * 65 + col] : 0.f;
            s += v;
            ss += v * v;
        }
        red[0][tid >> 6][col] = s;
        red[1][tid >> 6][col] = ss;
        __syncthreads();
        if (tid < 64) {
            float S = red[0][0][col] + red[0][1][col] + red[0][2][col] + red[0][3][col];
            atomicAdd(stats + col, S);
        } else if (tid < 128) {
            float SS = red[1][0][col] + red[1][1][col] + red[1][2][col] + red[1][3][col];
            atomicAdd(stats + 64 + col, SS);
        }
    }
}

// ---------------------------------------------------------------------------
// BatchNorm (batch stats, biased var) + affine + ReLU. In-place fp32 +
// dual-write bf16 copy (gather table for the next layer's agg).
// ---------------------------------------------------------------------------
__global__ __launch_bounds__(256)
void norm_kernel(float* h, const float* __restrict__ stats,
                 const float* __restrict__ g, const float* __restrict__ be,
                 __hip_bfloat16* __restrict__ xb) {
    size_t i4 = (size_t)blockIdx.x * 256 + threadIdx.x;
    if (i4 >= (size_t)NN * HD / 4) return;
    size_t off = i4 * 4;
    int col = (int)(off & 63);
    float4 v = *(const float4*)(h + off);
    float4 sm = *(const float4*)(stats + col);
    float4 sq = *(const float4*)(stats + 64 + col);
    float4 gg = *(const float4*)(g + col);
    float4 bb = *(const float4*)(be + col);
    const float inv = 1.f / (float)NN;
    float4 o;
    {
        float mu = sm.x * inv, var = sq.x * inv - mu * mu;
        float sc = gg.x * rsqrtf(var + BN_EPS);
        o.x = fmaxf((v.x - mu) * sc + bb.x, 0.f);
    }
    {
        float mu = sm.y * inv, var = sq.y * inv - mu * mu;
        float sc = gg.y * rsqrtf(var + BN_EPS);
        o.y = fmaxf((v.y - mu) * sc + bb.y, 0.f);
    }
    {
        float mu = sm.z * inv, var = sq.z * inv - mu * mu;
        float sc = gg.z * rsqrtf(var + BN_EPS);
        o.z = fmaxf((v.z - mu) * sc + bb.z, 0.f);
    }
    {
        float mu = sm.w * inv, var = sq.w * inv - mu * mu;
        float sc = gg.w * rsqrtf(var + BN_EPS);
        o.w = fmaxf((v.w - mu) * sc + bb.w, 0.f);
    }
    *(float4*)(h + off) = o;
    union { ushort4 u; __hip_bfloat16 b[4]; } p;
    p.b[0] = __float2bfloat16(o.x);
    p.b[1] = __float2bfloat16(o.y);
    p.b[2] = __float2bfloat16(o.z);
    p.b[3] = __float2bfloat16(o.w);
    *(ushort4*)((unsigned short*)xb + off) = p.u;
}

// ---------------------------------------------------------------------------
// Mean pool: 200 partial blocks + tiny finalize.
// ---------------------------------------------------------------------------
__global__ __launch_bounds__(256)
void pool_partial_kernel(const float* __restrict__ x, const int* __restrict__ batch,
                         float* __restrict__ sums) {
    int col = threadIdx.x & 63;
    int rl = threadIdx.x >> 6;
    int rs = blockIdx.x * 250;
    int re = rs + 250;
    int cur = -1;
    float acc = 0.f;
    for (int r = rs + rl; r < re; r += 4) {
        int g = batch[r];
        float v = x[(size_t)r * HD + col];
        if (g != cur) {
            if (cur >= 0) atomicAdd(&sums[cur * HD + col], acc);
            cur = g;
            acc = v;
        } else {
            acc += v;
        }
    }
    if (cur >= 0) atomicAdd(&sums[cur * HD + col], acc);
}

__device__ __forceinline__ int lower_bound_batch(const int* __restrict__ b, int val) {
    int lo = 0, hi = NN;
    while (lo < hi) {
        int mid = (lo + hi) >> 1;
        if (b[mid] < val) lo = mid + 1;
        else hi = mid;
    }
    return lo;
}

__global__ __launch_bounds__(1024)
void pool_finalize_kernel(const float* __restrict__ sums, const int* __restrict__ batch,
                          float* __restrict__ out) {
    int g = threadIdx.x >> 6;
    int col = threadIdx.x & 63;
    int s = lower_bound_batch(batch, g);
    int e = lower_bound_batch(batch, g + 1);
    float cnt = (float)(e - s);
    out[g * HD + col] = sums[g * HD + col] / fmaxf(cnt, 1.f);
}

extern "C" void kernel_launch(void* const* d_in, const int* in_sizes, int n_in,
                              void* d_out, int out_size, void* d_ws, size_t ws_size,
                              hipStream_t stream) {
    const float* x = (const float*)d_in[0];
    const int* ei = (const int*)d_in[1];
    const int* batch = (const int*)d_in[2];
    const float* W1_0 = (const float*)d_in[3];
    const float* b1_0 = (const float*)d_in[4];
    const float* W2_0 = (const float*)d_in[5];
    const float* b2_0 = (const float*)d_in[6];
    const float* g_0 = (const float*)d_in[7];
    const float* be_0 = (const float*)d_in[8];
    const float* W1_1 = (const float*)d_in[9];
    const float* b1_1 = (const float*)d_in[10];
    const float* W2_1 = (const float*)d_in[11];
    const float* b2_1 = (const float*)d_in[12];
    const float* g_1 = (const float*)d_in[13];
    const float* be_1 = (const float*)d_in[14];

    float* out = (float*)d_out;  // node output; also x1 staging between layers

    // workspace layout (~30 MB)
    float* buf_h = (float*)d_ws;                       // 3.2M f32 (agg output)
    float* stats = buf_h + (size_t)NN * HD;            // 128 f32
    float* psums = stats + 128;                        // 1024 f32
    int* row_ptr = (int*)(psums + 1024);               // NN+2
    int* cnt = row_ptr + (NN + 2);                     // NN (also cursor)
    int* partials = cnt + NN;                          // 256
    int* poffs = partials + 256;                       // 256
    int* csr = poffs + 256;                            // NE
    __hip_bfloat16* xb = (__hip_bfloat16*)(csr + NE);  // NN*HD bf16 (6.4MB)
    int2* part = (int2*)(xb + (size_t)NN * HD);        // NE int2 (6.4MB)
    int* bcur = (int*)(part + NE);                     // NBUCK

    dim3 b256(256);
    int egrid = (NE + 255) / 256;          // 3125
    int mlp_grid = (NN + 127) / 128;       // 391
    int norm_grid = (NN * HD / 4 + 255) / 256;
    int agg_grid = NN / 4;                 // 12500

    // ---- x->bf16 table + cnt zeroing, then CSR build ----
    x2bf_kernel<<<norm_grid, b256, 0, stream>>>(x, xb, cnt);
    count_kernel<<<egrid, b256, 0, stream>>>(ei, cnt);
    scan1_kernel<<<SCAN_BLOCKS, b256, 0, stream>>>(cnt, row_ptr, partials);
    scan2_kernel<<<1, b256, 0, stream>>>(partials, poffs);
    scan3_kernel<<<SCAN_BLOCKS, b256, 0, stream>>>(row_ptr, poffs, cnt, bcur);
    partition_kernel<<<egrid, b256, 0, stream>>>(ei, bcur, part);
    place2_kernel<<<NBUCK, b256, 0, stream>>>(part, row_ptr, cnt, csr);

    // ---- layer 0 ----
    agg_kernel<<<agg_grid, b256, 0, stream>>>(x, xb, row_ptr, csr, buf_h, stats);
    mlp_kernel<<<mlp_grid, b256, 0, stream>>>(buf_h, out, W1_0, b1_0, W2_0, b2_0, stats, psums);
    norm_kernel<<<norm_grid, b256, 0, stream>>>(out, stats, g_0, be_0, xb);

    // ---- layer 1 ----
    agg_kernel<<<agg_grid, b256, 0, stream>>>(out, xb, row_ptr, csr, buf_h, stats);
    mlp_kernel<<<mlp_grid, b256, 0, stream>>>(buf_h, out, W1_1, b1_1, W2_1, b2_1, stats, psums);
    norm_kernel<<<norm_grid, b256, 0, stream>>>(out, stats, g_1, be_1, xb);

    // ---- pool ----
    pool_partial_kernel<<<200, b256, 0, stream>>>(out, batch, psums);
    pool_finalize_kernel<<<1, dim3(1024), 0, stream>>>(psums, batch, out + (size_t)NN * HD);
}

// Round 10
// 359.439 us; speedup vs baseline: 1.4048x; 1.4048x over previous
//
#include <hip/hip_runtime.h>
#include <hip/hip_bf16.h>

// GIN: 2 x (CSR gather-sum + MLP(64->64->64) + BatchNorm + ReLU) + mean pool
// N=50000 nodes, E=800000 edges, H=64, G=16 graphs. fp32 in/out.
// R10: reverted R9's bucket partition (782-cursor atomic fan-in serialized:
// 191us vs 44us plain place). Agg split into two column-half passes: 3.2MB
// table per pass fits one XCD L2; each gather = exactly one 64B line.

constexpr int NN = 50000;
constexpr int NE = 800000;
constexpr int HD = 64;
constexpr int NG = 16;
constexpr float BN_EPS = 1e-5f;
constexpr int SCAN_BLOCKS = (NN + 255) / 256;  // 196

// ---------------------------------------------------------------------------
// CSR build: degree histogram -> exclusive scan -> edge placement (R7 form).
// ---------------------------------------------------------------------------
__global__ __launch_bounds__(256)
void count_kernel(const int* __restrict__ ei, int* __restrict__ cnt) {
    int e = blockIdx.x * 256 + threadIdx.x;
    if (e >= NE) return;
    atomicAdd(&cnt[ei[NE + e]], 1);
}

__global__ __launch_bounds__(256)
void scan1_kernel(const int* __restrict__ cnt, int* __restrict__ row_ptr,
                  int* __restrict__ partials) {
    int i = blockIdx.x * 256 + threadIdx.x;
    int v = (i < NN) ? cnt[i] : 0;
    __shared__ int s[256];
    s[threadIdx.x] = v;
    __syncthreads();
#pragma unroll
    for (int off = 1; off < 256; off <<= 1) {
        int add = (threadIdx.x >= off) ? s[threadIdx.x - off] : 0;
        __syncthreads();
        s[threadIdx.x] += add;
        __syncthreads();
    }
    if (i < NN) row_ptr[i] = s[threadIdx.x] - v;  // exclusive
    if (threadIdx.x == 255) partials[blockIdx.x] = s[255];
}

__global__ __launch_bounds__(256)
void scan2_kernel(int* __restrict__ partials, int* __restrict__ poffs) {
    int v = (threadIdx.x < SCAN_BLOCKS) ? partials[threadIdx.x] : 0;
    __shared__ int s[256];
    s[threadIdx.x] = v;
    __syncthreads();
#pragma unroll
    for (int off = 1; off < 256; off <<= 1) {
        int add = (threadIdx.x >= off) ? s[threadIdx.x - off] : 0;
        __syncthreads();
        s[threadIdx.x] += add;
        __syncthreads();
    }
    poffs[threadIdx.x] = s[threadIdx.x] - v;  // exclusive
}

__global__ __launch_bounds__(256)
void scan3_kernel(int* __restrict__ row_ptr, const int* __restrict__ poffs,
                  int* __restrict__ cursor) {
    int i = blockIdx.x * 256 + threadIdx.x;
    if (i < NN) {
        int v = row_ptr[i] + poffs[blockIdx.x];
        row_ptr[i] = v;
        cursor[i] = v;
    }
    if (i == 0) row_ptr[NN] = NE;
}

__global__ __launch_bounds__(256)
void place_kernel(const int* __restrict__ ei, int* __restrict__ cursor,
                  int* __restrict__ csr) {
    int e = blockIdx.x * 256 + threadIdx.x;
    if (e >= NE) return;
    int pos = atomicAdd(&cursor[ei[NE + e]], 1);
    csr[pos] = ei[e];
}

// ---------------------------------------------------------------------------
// fp32 -> bf16 table conversion. Also zeroes cnt[] for the following
// count_kernel (stream order guarantees completion first).
// ---------------------------------------------------------------------------
__global__ __launch_bounds__(256)
void x2bf_kernel(const float* __restrict__ x, __hip_bfloat16* __restrict__ xb,
                 int* __restrict__ cnt) {
    int i4 = blockIdx.x * 256 + threadIdx.x;
    if (i4 < NN) cnt[i4] = 0;
    if (i4 >= NN * HD / 4) return;
    float4 v = *(const float4*)(x + (size_t)i4 * 4);
    union { ushort4 u; __hip_bfloat16 b[4]; } p;
    p.b[0] = __float2bfloat16(v.x);
    p.b[1] = __float2bfloat16(v.y);
    p.b[2] = __float2bfloat16(v.z);
    p.b[3] = __float2bfloat16(v.w);
    *(ushort4*)((unsigned short*)xb + (size_t)i4 * 4) = p.u;
}

// ---------------------------------------------------------------------------
// Aggregation, one column-half per launch: h[r][c] = x[r][c] + sum_nb xb[nb][c]
// for c in [pass*32, pass*32+32). Wave = 2 rows x 32 cols; per-row neighbor
// gather reads exactly one 64B line of the 3.2MB half-table (XCD-L2-resident).
// Neighbor ids broadcast within each half via __shfl(ids, (lane&32)+j).
// Block 0 zeroes stats for the following mlp_kernel.
// ---------------------------------------------------------------------------
__global__ __launch_bounds__(256)
void agg_half_kernel(const float* __restrict__ x, const __hip_bfloat16* __restrict__ xb,
                     const int* __restrict__ row_ptr, const int* __restrict__ csr,
                     float* __restrict__ h, float* __restrict__ stats, int pass) {
    if (blockIdx.x == 0 && threadIdx.x < 128) stats[threadIdx.x] = 0.f;
    int tid = threadIdx.x;
    int lane = tid & 63;
    int i31 = lane & 31;
    int hb = lane & 32;                         // half base for shfl source
    int row = blockIdx.x * 8 + (tid >> 6) * 2 + (lane >> 5);
    int col = pass * 32 + i31;
    int s = row_ptr[row], e = row_ptr[row + 1];
    int cnt = e - s;
    int ids = (i31 < cnt) ? csr[s + i31] : 0;   // first 32 neighbor ids of my row
    float acc = x[(size_t)row * HD + col];
    int m = min(cnt, 32);
    int j = 0;
    float a0 = 0.f, a1 = 0.f, a2 = 0.f, a3 = 0.f;
    float a4 = 0.f, a5 = 0.f, a6 = 0.f, a7 = 0.f;
    for (; j + 8 <= m; j += 8) {
        int nb0 = __shfl(ids, hb + j);
        int nb1 = __shfl(ids, hb + j + 1);
        int nb2 = __shfl(ids, hb + j + 2);
        int nb3 = __shfl(ids, hb + j + 3);
        int nb4 = __shfl(ids, hb + j + 4);
        int nb5 = __shfl(ids, hb + j + 5);
        int nb6 = __shfl(ids, hb + j + 6);
        int nb7 = __shfl(ids, hb + j + 7);
        float v0 = __bfloat162float(xb[(size_t)nb0 * HD + col]);
        float v1 = __bfloat162float(xb[(size_t)nb1 * HD + col]);
        float v2 = __bfloat162float(xb[(size_t)nb2 * HD + col]);
        float v3 = __bfloat162float(xb[(size_t)nb3 * HD + col]);
        float v4 = __bfloat162float(xb[(size_t)nb4 * HD + col]);
        float v5 = __bfloat162float(xb[(size_t)nb5 * HD + col]);
        float v6 = __bfloat162float(xb[(size_t)nb6 * HD + col]);
        float v7 = __bfloat162float(xb[(size_t)nb7 * HD + col]);
        a0 += v0; a1 += v1; a2 += v2; a3 += v3;
        a4 += v4; a5 += v5; a6 += v6; a7 += v7;
    }
    acc += ((a0 + a1) + (a2 + a3)) + ((a4 + a5) + (a6 + a7));
    for (; j < m; j++) {
        int nb = __shfl(ids, hb + j);
        acc += __bfloat162float(xb[(size_t)nb * HD + col]);
    }
    if (cnt > 32) {  // rare (Poisson(16)); whole half enters uniformly
        int ids2 = (32 + i31 < cnt) ? csr[s + 32 + i31] : 0;
        int m2 = min(cnt, 64);
        for (j = 32; j < m2; j++) {
            int nb = __shfl(ids2, hb + (j - 32));
            acc += __bfloat162float(xb[(size_t)nb * HD + col]);
        }
        for (j = 64; j < cnt; j++)
            acc += __bfloat162float(xb[(size_t)csr[s + j] * HD + col]);
    }
    h[(size_t)row * HD + col] = acc;
}

// ---------------------------------------------------------------------------
// Fused MLP + BN-stats epilogue. hout = ReLU(hin @ W1 + b1) @ W2 + b2.
// Block = 128 rows x 256 threads; wave wv owns cols [wv*16,+16); thread does
// rows lane and lane+64. One LDS tile reused input->t->output (barriered).
// Block 0 zeroes psums (only touched by pool kernels, 2 dispatches later).
// ---------------------------------------------------------------------------
__global__ __launch_bounds__(256)
void mlp_kernel(const float* __restrict__ hin, float* __restrict__ hout,
                const float* __restrict__ W1, const float* __restrict__ b1,
                const float* __restrict__ W2, const float* __restrict__ b2,
                float* __restrict__ stats, float* __restrict__ psums) {
    __shared__ float sh[128 * 65];
    __shared__ float sW[64 * 64];
    __shared__ float sb[64];
    __shared__ float red[2][4][64];
    int tid = threadIdx.x;
    int base = blockIdx.x * 128;

    if (blockIdx.x == 0) {
        float4 z = make_float4(0.f, 0.f, 0.f, 0.f);
        *(float4*)(psums + tid * 4) = z;
    }
    for (int i = tid; i < 4096; i += 256) sW[i] = W1[i];
    if (tid < 64) sb[tid] = b1[tid];
#pragma unroll
    for (int i = 0; i < 8; i++) {
        int i4 = tid + 256 * i;          // 0..2047 float4s
        int row = i4 >> 4, col = (i4 & 15) * 4;
        int grow = base + row;
        float4 v = (grow < NN) ? *(const float4*)(hin + (size_t)grow * HD + col)
                               : make_float4(0.f, 0.f, 0.f, 0.f);
        float* d = sh + row * 65 + col;
        d[0] = v.x; d[1] = v.y; d[2] = v.z; d[3] = v.w;
    }
    __syncthreads();

    int wv = tid >> 6;
    int lane = tid & 63;

    float acc0[16], acc1[16];
    // ---- GEMM1 ----
#pragma unroll
    for (int j = 0; j < 16; j++) { acc0[j] = sb[wv * 16 + j]; acc1[j] = acc0[j]; }
    for (int k = 0; k < 64; k++) {
        float a0 = sh[lane * 65 + k];
        float a1 = sh[(64 + lane) * 65 + k];
        const float4* wr = (const float4*)(sW + k * 64 + wv * 16);
#pragma unroll
        for (int q = 0; q < 4; q++) {
            float4 w = wr[q];
            acc0[4 * q + 0] = fmaf(a0, w.x, acc0[4 * q + 0]);
            acc0[4 * q + 1] = fmaf(a0, w.y, acc0[4 * q + 1]);
            acc0[4 * q + 2] = fmaf(a0, w.z, acc0[4 * q + 2]);
            acc0[4 * q + 3] = fmaf(a0, w.w, acc0[4 * q + 3]);
            acc1[4 * q + 0] = fmaf(a1, w.x, acc1[4 * q + 0]);
            acc1[4 * q + 1] = fmaf(a1, w.y, acc1[4 * q + 1]);
            acc1[4 * q + 2] = fmaf(a1, w.z, acc1[4 * q + 2]);
            acc1[4 * q + 3] = fmaf(a1, w.w, acc1[4 * q + 3]);
        }
    }
    __syncthreads();  // all input reads of sh + W1 reads of sW complete

    // t = ReLU(acc) overwrites sh; restage W2/b2
#pragma unroll
    for (int j = 0; j < 16; j++) {
        sh[lane * 65 + wv * 16 + j] = fmaxf(acc0[j], 0.f);
        sh[(64 + lane) * 65 + wv * 16 + j] = fmaxf(acc1[j], 0.f);
    }
    for (int i = tid; i < 4096; i += 256) sW[i] = W2[i];
    if (tid < 64) sb[tid] = b2[tid];
    __syncthreads();

    // ---- GEMM2 ----
#pragma unroll
    for (int j = 0; j < 16; j++) { acc0[j] = sb[wv * 16 + j]; acc1[j] = acc0[j]; }
    for (int k = 0; k < 64; k++) {
        float a0 = sh[lane * 65 + k];
        float a1 = sh[(64 + lane) * 65 + k];
        const float4* wr = (const float4*)(sW + k * 64 + wv * 16);
#pragma unroll
        for (int q = 0; q < 4; q++) {
            float4 w = wr[q];
            acc0[4 * q + 0] = fmaf(a0, w.x, acc0[4 * q + 0]);
            acc0[4 * q + 1] = fmaf(a0, w.y, acc0[4 * q + 1]);
            acc0[4 * q + 2] = fmaf(a0, w.z, acc0[4 * q + 2]);
            acc0[4 * q + 3] = fmaf(a0, w.w, acc0[4 * q + 3]);
            acc1[4 * q + 0] = fmaf(a1, w.x, acc1[4 * q + 0]);
            acc1[4 * q + 1] = fmaf(a1, w.y, acc1[4 * q + 1]);
            acc1[4 * q + 2] = fmaf(a1, w.z, acc1[4 * q + 2]);
            acc1[4 * q + 3] = fmaf(a1, w.w, acc1[4 * q + 3]);
        }
    }
    __syncthreads();  // all t reads complete before overwrite
#pragma unroll
    for (int j = 0; j < 16; j++) {
        sh[lane * 65 + wv * 16 + j] = acc0[j];
        sh[(64 + lane) * 65 + wv * 16 + j] = acc1[j];
    }
    __syncthreads();

    // coalesced store (float4)
#pragma unroll
    for (int i = 0; i < 8; i++) {
        int i4 = tid + 256 * i;
        int row = i4 >> 4, col = (i4 & 15) * 4;
        int grow = base + row;
        if (grow < NN) {
            const float* s = sh + row * 65 + col;
            *(float4*)(hout + (size_t)grow * HD + col) =
                make_float4(s[0], s[1], s[2], s[3]);
        }
    }

    // ---- fused BN-stats partials over the output tile ----
    {
        int col = tid & 63;
        int r0 = (tid >> 6) * 32;
        float s = 0.f, ss = 0.f;
#pragma unroll
        for (int r = 0; r < 32; r++) {
            float v = (base + r0 + r < NN) ? sh[(r0 + r) * 65 + col] : 0.f;
            s += v;
            ss += v * v;
        }
        red[0][tid >> 6][col] = s;
        red[1][tid >> 6][col] = ss;
        __syncthreads();
        if (tid < 64) {
            float S = red[0][0][col] + red[0][1][col] + red[0][2][col] + red[0][3][col];
            atomicAdd(stats + col, S);
        } else if (tid < 128) {
            float SS = red[1][0][col] + red[1][1][col] + red[1][2][col] + red[1][3][col];
            atomicAdd(stats + 64 + col, SS);
        }
    }
}

// ---------------------------------------------------------------------------
// BatchNorm (batch stats, biased var) + affine + ReLU. In-place fp32 +
// dual-write bf16 copy (gather table for the next layer's agg).
// ---------------------------------------------------------------------------
__global__ __launch_bounds__(256)
void norm_kernel(float* h, const float* __restrict__ stats,
                 const float* __restrict__ g, const float* __restrict__ be,
                 __hip_bfloat16* __restrict__ xb) {
    size_t i4 = (size_t)blockIdx.x * 256 + threadIdx.x;
    if (i4 >= (size_t)NN * HD / 4) return;
    size_t off = i4 * 4;
    int col = (int)(off & 63);
    float4 v = *(const float4*)(h + off);
    float4 sm = *(const float4*)(stats + col);
    float4 sq = *(const float4*)(stats + 64 + col);
    float4 gg = *(const float4*)(g + col);
    float4 bb = *(const float4*)(be + col);
    const float inv = 1.f / (float)NN;
    float4 o;
    {
        float mu = sm.x * inv, var = sq.x * inv - mu * mu;
        float sc = gg.x * rsqrtf(var + BN_EPS);
        o.x = fmaxf((v.x - mu) * sc + bb.x, 0.f);
    }
    {
        float mu = sm.y * inv, var = sq.y * inv - mu * mu;
        float sc = gg.y * rsqrtf(var + BN_EPS);
        o.y = fmaxf((v.y - mu) * sc + bb.y, 0.f);
    }
    {
        float mu = sm.z * inv, var = sq.z * inv - mu * mu;
        float sc = gg.z * rsqrtf(var + BN_EPS);
        o.z = fmaxf((v.z - mu) * sc + bb.z, 0.f);
    }
    {
        float mu = sm.w * inv, var = sq.w * inv - mu * mu;
        float sc = gg.w * rsqrtf(var + BN_EPS);
        o.w = fmaxf((v.w - mu) * sc + bb.w, 0.f);
    }
    *(float4*)(h + off) = o;
    union { ushort4 u; __hip_bfloat16 b[4]; } p;
    p.b[0] = __float2bfloat16(o.x);
    p.b[1] = __float2bfloat16(o.y);
    p.b[2] = __float2bfloat16(o.z);
    p.b[3] = __float2bfloat16(o.w);
    *(ushort4*)((unsigned short*)xb + off) = p.u;
}

// ---------------------------------------------------------------------------
// Mean pool: 200 partial blocks + tiny finalize.
// ---------------------------------------------------------------------------
__global__ __launch_bounds__(256)
void pool_partial_kernel(const float* __restrict__ x, const int* __restrict__ batch,
                         float* __restrict__ sums) {
    int col = threadIdx.x & 63;
    int rl = threadIdx.x >> 6;
    int rs = blockIdx.x * 250;
    int re = rs + 250;
    int cur = -1;
    float acc = 0.f;
    for (int r = rs + rl; r < re; r += 4) {
        int g = batch[r];
        float v = x[(size_t)r * HD + col];
        if (g != cur) {
            if (cur >= 0) atomicAdd(&sums[cur * HD + col], acc);
            cur = g;
            acc = v;
        } else {
            acc += v;
        }
    }
    if (cur >= 0) atomicAdd(&sums[cur * HD + col], acc);
}

__device__ __forceinline__ int lower_bound_batch(const int* __restrict__ b, int val) {
    int lo = 0, hi = NN;
    while (lo < hi) {
        int mid = (lo + hi) >> 1;
        if (b[mid] < val) lo = mid + 1;
        else hi = mid;
    }
    return lo;
}

__global__ __launch_bounds__(1024)
void pool_finalize_kernel(const float* __restrict__ sums, const int* __restrict__ batch,
                          float* __restrict__ out) {
    int g = threadIdx.x >> 6;
    int col = threadIdx.x & 63;
    int s = lower_bound_batch(batch, g);
    int e = lower_bound_batch(batch, g + 1);
    float cnt = (float)(e - s);
    out[g * HD + col] = sums[g * HD + col] / fmaxf(cnt, 1.f);
}

extern "C" void kernel_launch(void* const* d_in, const int* in_sizes, int n_in,
                              void* d_out, int out_size, void* d_ws, size_t ws_size,
                              hipStream_t stream) {
    const float* x = (const float*)d_in[0];
    const int* ei = (const int*)d_in[1];
    const int* batch = (const int*)d_in[2];
    const float* W1_0 = (const float*)d_in[3];
    const float* b1_0 = (const float*)d_in[4];
    const float* W2_0 = (const float*)d_in[5];
    const float* b2_0 = (const float*)d_in[6];
    const float* g_0 = (const float*)d_in[7];
    const float* be_0 = (const float*)d_in[8];
    const float* W1_1 = (const float*)d_in[9];
    const float* b1_1 = (const float*)d_in[10];
    const float* W2_1 = (const float*)d_in[11];
    const float* b2_1 = (const float*)d_in[12];
    const float* g_1 = (const float*)d_in[13];
    const float* be_1 = (const float*)d_in[14];

    float* out = (float*)d_out;  // node output; also x1 staging between layers

    // workspace layout (~23 MB)
    float* buf_h = (float*)d_ws;                       // 3.2M f32 (agg output)
    float* stats = buf_h + (size_t)NN * HD;            // 128 f32
    float* psums = stats + 128;                        // 1024 f32
    int* row_ptr = (int*)(psums + 1024);               // NN+2
    int* cnt = row_ptr + (NN + 2);                     // NN (also cursor)
    int* partials = cnt + NN;                          // 256
    int* poffs = partials + 256;                       // 256
    int* csr = poffs + 256;                            // NE
    __hip_bfloat16* xb = (__hip_bfloat16*)(csr + NE);  // NN*HD bf16 (6.4MB)

    dim3 b256(256);
    int egrid = (NE + 255) / 256;          // 3125
    int mlp_grid = (NN + 127) / 128;       // 391
    int norm_grid = (NN * HD / 4 + 255) / 256;
    int aggh_grid = NN / 8;                // 6250 (8 rows per block)

    // ---- x->bf16 table + cnt zeroing, then CSR build ----
    x2bf_kernel<<<norm_grid, b256, 0, stream>>>(x, xb, cnt);
    count_kernel<<<egrid, b256, 0, stream>>>(ei, cnt);
    scan1_kernel<<<SCAN_BLOCKS, b256, 0, stream>>>(cnt, row_ptr, partials);
    scan2_kernel<<<1, b256, 0, stream>>>(partials, poffs);
    scan3_kernel<<<SCAN_BLOCKS, b256, 0, stream>>>(row_ptr, poffs, cnt);
    place_kernel<<<egrid, b256, 0, stream>>>(ei, cnt, csr);

    // ---- layer 0 ----
    agg_half_kernel<<<aggh_grid, b256, 0, stream>>>(x, xb, row_ptr, csr, buf_h, stats, 0);
    agg_half_kernel<<<aggh_grid, b256, 0, stream>>>(x, xb, row_ptr, csr, buf_h, stats, 1);
    mlp_kernel<<<mlp_grid, b256, 0, stream>>>(buf_h, out, W1_0, b1_0, W2_0, b2_0, stats, psums);
    norm_kernel<<<norm_grid, b256, 0, stream>>>(out, stats, g_0, be_0, xb);

    // ---- layer 1 ----
    agg_half_kernel<<<aggh_grid, b256, 0, stream>>>(out, xb, row_ptr, csr, buf_h, stats, 0);
    agg_half_kernel<<<aggh_grid, b256, 0, stream>>>(out, xb, row_ptr, csr, buf_h, stats, 1);
    mlp_kernel<<<mlp_grid, b256, 0, stream>>>(buf_h, out, W1_1, b1_1, W2_1, b2_1, stats, psums);
    norm_kernel<<<norm_grid, b256, 0, stream>>>(out, stats, g_1, be_1, xb);

    // ---- pool ----
    pool_partial_kernel<<<200, b256, 0, stream>>>(out, batch, psums);
    pool_finalize_kernel<<<1, dim3(1024), 0, stream>>>(psums, batch, out + (size_t)NN * HD);
}

// Round 11
// 329.349 us; speedup vs baseline: 1.5332x; 1.0914x over previous
//
#include <hip/hip_runtime.h>
#include <hip/hip_bf16.h>

// GIN: 2 x (CSR gather-sum + MLP(64->64->64) + BatchNorm + ReLU) + mean pool
// N=50000 nodes, E=800000 edges, H=64, G=16 graphs. fp32 in/out.
// R11: agg reverted to R7 full-width form (R10 column-halves: same line count,
// 2x csr reads -> +28us). CSR placement: LDS-binned two-level partition --
// pass1 9.6K chunk-claim atomics + coalesced pair writes (R9 died on 800K
// atomics->49 lines), pass2 LDS row-cursors + block-local 64KB csr windows
// (R7/R8 died on 51MB scattered write-allocate). scan2 folded into scan3.

constexpr int NN = 50000;
constexpr int NE = 800000;
constexpr int HD = 64;
constexpr int NG = 16;
constexpr float BN_EPS = 1e-5f;
constexpr int SCAN_BLOCKS = (NN + 255) / 256;  // 196
constexpr int NBUCK = (NN + 1023) / 1024;      // 49 coarse buckets (dst>>10)
constexpr int BIN1_BLOCKS = (NE + 4095) / 4096;  // 196

// ---------------------------------------------------------------------------
// Degree histogram.
// ---------------------------------------------------------------------------
__global__ __launch_bounds__(256)
void count_kernel(const int* __restrict__ ei, int* __restrict__ cnt) {
    int e = blockIdx.x * 256 + threadIdx.x;
    if (e >= NE) return;
    atomicAdd(&cnt[ei[NE + e]], 1);
}

// Per-256-chunk scan; exclusive values + per-block totals.
__global__ __launch_bounds__(256)
void scan1_kernel(const int* __restrict__ cnt, int* __restrict__ row_ptr,
                  int* __restrict__ partials) {
    int i = blockIdx.x * 256 + threadIdx.x;
    int v = (i < NN) ? cnt[i] : 0;
    __shared__ int s[256];
    s[threadIdx.x] = v;
    __syncthreads();
#pragma unroll
    for (int off = 1; off < 256; off <<= 1) {
        int add = (threadIdx.x >= off) ? s[threadIdx.x - off] : 0;
        __syncthreads();
        s[threadIdx.x] += add;
        __syncthreads();
    }
    if (i < NN) row_ptr[i] = s[threadIdx.x] - v;  // exclusive
    if (threadIdx.x == 255) partials[blockIdx.x] = s[255];
}

// Finalize scan: each block redundantly prefix-sums the 196 partials (cheap),
// adds its offset, and seeds the coarse-bucket base cursors. Replaces scan2.
__global__ __launch_bounds__(256)
void scan3_kernel(int* __restrict__ row_ptr, const int* __restrict__ partials,
                  int* __restrict__ gcur) {
    __shared__ int s[256];
    __shared__ int orig[256];
    int v = (threadIdx.x < SCAN_BLOCKS) ? partials[threadIdx.x] : 0;
    s[threadIdx.x] = v;
    orig[threadIdx.x] = v;
    __syncthreads();
#pragma unroll
    for (int off = 1; off < 256; off <<= 1) {
        int add = (threadIdx.x >= off) ? s[threadIdx.x - off] : 0;
        __syncthreads();
        s[threadIdx.x] += add;
        __syncthreads();
    }
    int poff = s[blockIdx.x] - orig[blockIdx.x];  // exclusive block offset
    int i = blockIdx.x * 256 + threadIdx.x;
    if (i < NN) {
        int rv = row_ptr[i] + poff;
        row_ptr[i] = rv;
        if ((i & 1023) == 0) gcur[i >> 10] = rv;  // coarse bucket base
    }
    if (i == 0) row_ptr[NN] = NE;
}

// Pass 1: LDS-binned partition into 49 coarse dst-buckets. Per block: local
// histogram -> one global chunk claim per bucket (9.6K atomics total) ->
// pair writes, contiguous within each (block,bucket) chunk.
__global__ __launch_bounds__(256)
void bin1_kernel(const int* __restrict__ ei, int* __restrict__ gcur,
                 int2* __restrict__ part) {
    __shared__ int lcnt[NBUCK];
    __shared__ int lbase[NBUCK];
    __shared__ int lcur[NBUCK];
    int tid = threadIdx.x;
    int chunk = blockIdx.x * 4096;
    if (tid < NBUCK) lcnt[tid] = 0;
    __syncthreads();
#pragma unroll
    for (int r = 0; r < 16; r++) {
        int e = chunk + r * 256 + tid;
        if (e < NE) atomicAdd(&lcnt[ei[NE + e] >> 10], 1);
    }
    __syncthreads();
    if (tid < NBUCK) {
        lbase[tid] = atomicAdd(&gcur[tid], lcnt[tid]);
        lcur[tid] = 0;
    }
    __syncthreads();
#pragma unroll
    for (int r = 0; r < 16; r++) {
        int e = chunk + r * 256 + tid;
        if (e < NE) {
            int src = ei[e];
            int b = ei[NE + e] >> 10;
            int slot = atomicAdd(&lcur[b], 1);
            part[lbase[b] + slot] = make_int2(src, ei[NE + e]);
        }
    }
}

// Pass 2: one block per coarse bucket. Row cursors live in LDS; csr writes
// confined to this bucket's contiguous window (block-local -> full lines).
__global__ __launch_bounds__(256)
void bin2_kernel(const int2* __restrict__ part, const int* __restrict__ row_ptr,
                 int* __restrict__ csr) {
    __shared__ int lcur[1024];
    int b = blockIdx.x;
    int base_row = b << 10;
    for (int i = threadIdx.x; i < 1024; i += 256)
        lcur[i] = row_ptr[min(base_row + i, NN)];
    __syncthreads();
    int s = row_ptr[min(base_row, NN)];
    int e = row_ptr[min(base_row + 1024, NN)];
    for (int i = s + threadIdx.x; i < e; i += 256) {
        int2 p = part[i];
        int pos = atomicAdd(&lcur[p.y & 1023], 1);
        csr[pos] = p.x;
    }
}

// ---------------------------------------------------------------------------
// fp32 -> bf16 table conversion; also zeroes cnt[] for count_kernel.
// ---------------------------------------------------------------------------
__global__ __launch_bounds__(256)
void x2bf_kernel(const float* __restrict__ x, __hip_bfloat16* __restrict__ xb,
                 int* __restrict__ cnt) {
    int i4 = blockIdx.x * 256 + threadIdx.x;
    if (i4 < NN) cnt[i4] = 0;
    if (i4 >= NN * HD / 4) return;
    float4 v = *(const float4*)(x + (size_t)i4 * 4);
    union { ushort4 u; __hip_bfloat16 b[4]; } p;
    p.b[0] = __float2bfloat16(v.x);
    p.b[1] = __float2bfloat16(v.y);
    p.b[2] = __float2bfloat16(v.z);
    p.b[3] = __float2bfloat16(v.w);
    *(ushort4*)((unsigned short*)xb + (size_t)i4 * 4) = p.u;
}

// ---------------------------------------------------------------------------
// Aggregation (R7 form): one wave per dst row, 8-deep gather pipeline.
// h[r] = x_f32[r] + sum_nb bf16(x)[nb]. Block 0 zeroes stats.
// ---------------------------------------------------------------------------
__global__ __launch_bounds__(256)
void agg_kernel(const float* __restrict__ x, const __hip_bfloat16* __restrict__ xb,
                const int* __restrict__ row_ptr, const int* __restrict__ csr,
                float* __restrict__ h, float* __restrict__ stats) {
    if (blockIdx.x == 0 && threadIdx.x < 128) stats[threadIdx.x] = 0.f;
    int row = blockIdx.x * 4 + (threadIdx.x >> 6);
    int lane = threadIdx.x & 63;
    int s = row_ptr[row], e = row_ptr[row + 1];
    int cnt = e - s;
    int ids = (lane < cnt) ? csr[s + lane] : 0;
    float acc = x[(size_t)row * HD + lane];
    int m = min(cnt, 64);
    int j = 0;
    float a0 = 0.f, a1 = 0.f, a2 = 0.f, a3 = 0.f;
    float a4 = 0.f, a5 = 0.f, a6 = 0.f, a7 = 0.f;
    for (; j + 8 <= m; j += 8) {
        int nb0 = __shfl(ids, j);
        int nb1 = __shfl(ids, j + 1);
        int nb2 = __shfl(ids, j + 2);
        int nb3 = __shfl(ids, j + 3);
        int nb4 = __shfl(ids, j + 4);
        int nb5 = __shfl(ids, j + 5);
        int nb6 = __shfl(ids, j + 6);
        int nb7 = __shfl(ids, j + 7);
        float v0 = __bfloat162float(xb[(size_t)nb0 * HD + lane]);
        float v1 = __bfloat162float(xb[(size_t)nb1 * HD + lane]);
        float v2 = __bfloat162float(xb[(size_t)nb2 * HD + lane]);
        float v3 = __bfloat162float(xb[(size_t)nb3 * HD + lane]);
        float v4 = __bfloat162float(xb[(size_t)nb4 * HD + lane]);
        float v5 = __bfloat162float(xb[(size_t)nb5 * HD + lane]);
        float v6 = __bfloat162float(xb[(size_t)nb6 * HD + lane]);
        float v7 = __bfloat162float(xb[(size_t)nb7 * HD + lane]);
        a0 += v0; a1 += v1; a2 += v2; a3 += v3;
        a4 += v4; a5 += v5; a6 += v6; a7 += v7;
    }
    acc += ((a0 + a1) + (a2 + a3)) + ((a4 + a5) + (a6 + a7));
    for (; j < m; j++) {
        int nb = __shfl(ids, j);
        acc += __bfloat162float(xb[(size_t)nb * HD + lane]);
    }
    for (int jj = s + 64; jj < e; jj++) {  // degree > 64 fallback
        acc += __bfloat162float(xb[(size_t)csr[jj] * HD + lane]);
    }
    h[(size_t)row * HD + lane] = acc;
}

// ---------------------------------------------------------------------------
// Fused MLP + BN-stats epilogue. hout = ReLU(hin @ W1 + b1) @ W2 + b2.
// Block = 128 rows x 256 threads; wave wv owns cols [wv*16,+16); thread does
// rows lane and lane+64. One LDS tile reused input->t->output (barriered).
// Block 0 zeroes psums (only touched by pool kernels, 2 dispatches later).
// ---------------------------------------------------------------------------
__global__ __launch_bounds__(256)
void mlp_kernel(const float* __restrict__ hin, float* __restrict__ hout,
                const float* __restrict__ W1, const float* __restrict__ b1,
                const float* __restrict__ W2, const float* __restrict__ b2,
                float* __restrict__ stats, float* __restrict__ psums) {
    __shared__ float sh[128 * 65];
    __shared__ float sW[64 * 64];
    __shared__ float sb[64];
    __shared__ float red[2][4][64];
    int tid = threadIdx.x;
    int base = blockIdx.x * 128;

    if (blockIdx.x == 0) {
        float4 z = make_float4(0.f, 0.f, 0.f, 0.f);
        *(float4*)(psums + tid * 4) = z;
    }
    for (int i = tid; i < 4096; i += 256) sW[i] = W1[i];
    if (tid < 64) sb[tid] = b1[tid];
#pragma unroll
    for (int i = 0; i < 8; i++) {
        int i4 = tid + 256 * i;          // 0..2047 float4s
        int row = i4 >> 4, col = (i4 & 15) * 4;
        int grow = base + row;
        float4 v = (grow < NN) ? *(const float4*)(hin + (size_t)grow * HD + col)
                               : make_float4(0.f, 0.f, 0.f, 0.f);
        float* d = sh + row * 65 + col;
        d[0] = v.x; d[1] = v.y; d[2] = v.z; d[3] = v.w;
    }
    __syncthreads();

    int wv = tid >> 6;
    int lane = tid & 63;

    float acc0[16], acc1[16];
    // ---- GEMM1 ----
#pragma unroll
    for (int j = 0; j < 16; j++) { acc0[j] = sb[wv * 16 + j]; acc1[j] = acc0[j]; }
    for (int k = 0; k < 64; k++) {
        float a0 = sh[lane * 65 + k];
        float a1 = sh[(64 + lane) * 65 + k];
        const float4* wr = (const float4*)(sW + k * 64 + wv * 16);
#pragma unroll
        for (int q = 0; q < 4; q++) {
            float4 w = wr[q];
            acc0[4 * q + 0] = fmaf(a0, w.x, acc0[4 * q + 0]);
            acc0[4 * q + 1] = fmaf(a0, w.y, acc0[4 * q + 1]);
            acc0[4 * q + 2] = fmaf(a0, w.z, acc0[4 * q + 2]);
            acc0[4 * q + 3] = fmaf(a0, w.w, acc0[4 * q + 3]);
            acc1[4 * q + 0] = fmaf(a1, w.x, acc1[4 * q + 0]);
            acc1[4 * q + 1] = fmaf(a1, w.y, acc1[4 * q + 1]);
            acc1[4 * q + 2] = fmaf(a1, w.z, acc1[4 * q + 2]);
            acc1[4 * q + 3] = fmaf(a1, w.w, acc1[4 * q + 3]);
        }
    }
    __syncthreads();  // all input reads of sh + W1 reads of sW complete

    // t = ReLU(acc) overwrites sh; restage W2/b2
#pragma unroll
    for (int j = 0; j < 16; j++) {
        sh[lane * 65 + wv * 16 + j] = fmaxf(acc0[j], 0.f);
        sh[(64 + lane) * 65 + wv * 16 + j] = fmaxf(acc1[j], 0.f);
    }
    for (int i = tid; i < 4096; i += 256) sW[i] = W2[i];
    if (tid < 64) sb[tid] = b2[tid];
    __syncthreads();

    // ---- GEMM2 ----
#pragma unroll
    for (int j = 0; j < 16; j++) { acc0[j] = sb[wv * 16 + j]; acc1[j] = acc0[j]; }
    for (int k = 0; k < 64; k++) {
        float a0 = sh[lane * 65 + k];
        float a1 = sh[(64 + lane) * 65 + k];
        const float4* wr = (const float4*)(sW + k * 64 + wv * 16);
#pragma unroll
        for (int q = 0; q < 4; q++) {
            float4 w = wr[q];
            acc0[4 * q + 0] = fmaf(a0, w.x, acc0[4 * q + 0]);
            acc0[4 * q + 1] = fmaf(a0, w.y, acc0[4 * q + 1]);
            acc0[4 * q + 2] = fmaf(a0, w.z, acc0[4 * q + 2]);
            acc0[4 * q + 3] = fmaf(a0, w.w, acc0[4 * q + 3]);
            acc1[4 * q + 0] = fmaf(a1, w.x, acc1[4 * q + 0]);
            acc1[4 * q + 1] = fmaf(a1, w.y, acc1[4 * q + 1]);
            acc1[4 * q + 2] = fmaf(a1, w.z, acc1[4 * q + 2]);
            acc1[4 * q + 3] = fmaf(a1, w.w, acc1[4 * q + 3]);
        }
    }
    __syncthreads();  // all t reads complete before overwrite
#pragma unroll
    for (int j = 0; j < 16; j++) {
        sh[lane * 65 + wv * 16 + j] = acc0[j];
        sh[(64 + lane) * 65 + wv * 16 + j] = acc1[j];
    }
    __syncthreads();

    // coalesced store (float4)
#pragma unroll
    for (int i = 0; i < 8; i++) {
        int i4 = tid + 256 * i;
        int row = i4 >> 4, col = (i4 & 15) * 4;
        int grow = base + row;
        if (grow < NN) {
            const float* s = sh + row * 65 + col;
            *(float4*)(hout + (size_t)grow * HD + col) =
                make_float4(s[0], s[1], s[2], s[3]);
        }
    }

    // ---- fused BN-stats partials over the output tile ----
    {
        int col = tid & 63;
        int r0 = (tid >> 6) * 32;
        float s = 0.f, ss = 0.f;
#pragma unroll
        for (int r = 0; r < 32; r++) {
            float v = (base + r0 + r < NN) ? sh[(r0 + r) * 65 + col] : 0.f;
            s += v;
            ss += v * v;
        }
        red[0][tid >> 6][col] = s;
        red[1][tid >> 6][col] = ss;
        __syncthreads();
        if (tid < 64) {
            float S = red[0][0][col] + red[0][1][col] + red[0][2][col] + red[0][3][col];
            atomicAdd(stats + col, S);
        } else if (tid < 128) {
            float SS = red[1][0][col] + red[1][1][col] + red[1][2][col] + red[1][3][col];
            atomicAdd(stats + 64 + col, SS);
        }
    }
}

// ---------------------------------------------------------------------------
// BatchNorm (batch stats, biased var) + affine + ReLU. In-place fp32 +
// dual-write bf16 copy (gather table for the next layer's agg).
// ---------------------------------------------------------------------------
__global__ __launch_bounds__(256)
void norm_kernel(float* h, const float* __restrict__ stats,
                 const float* __restrict__ g, const float* __restrict__ be,
                 __hip_bfloat16* __restrict__ xb) {
    size_t i4 = (size_t)blockIdx.x * 256 + threadIdx.x;
    if (i4 >= (size_t)NN * HD / 4) return;
    size_t off = i4 * 4;
    int col = (int)(off & 63);
    float4 v = *(const float4*)(h + off);
    float4 sm = *(const float4*)(stats + col);
    float4 sq = *(const float4*)(stats + 64 + col);
    float4 gg = *(const float4*)(g + col);
    float4 bb = *(const float4*)(be + col);
    const float inv = 1.f / (float)NN;
    float4 o;
    {
        float mu = sm.x * inv, var = sq.x * inv - mu * mu;
        float sc = gg.x * rsqrtf(var + BN_EPS);
        o.x = fmaxf((v.x - mu) * sc + bb.x, 0.f);
    }
    {
        float mu = sm.y * inv, var = sq.y * inv - mu * mu;
        float sc = gg.y * rsqrtf(var + BN_EPS);
        o.y = fmaxf((v.y - mu) * sc + bb.y, 0.f);
    }
    {
        float mu = sm.z * inv, var = sq.z * inv - mu * mu;
        float sc = gg.z * rsqrtf(var + BN_EPS);
        o.z = fmaxf((v.z - mu) * sc + bb.z, 0.f);
    }
    {
        float mu = sm.w * inv, var = sq.w * inv - mu * mu;
        float sc = gg.w * rsqrtf(var + BN_EPS);
        o.w = fmaxf((v.w - mu) * sc + bb.w, 0.f);
    }
    *(float4*)(h + off) = o;
    union { ushort4 u; __hip_bfloat16 b[4]; } p;
    p.b[0] = __float2bfloat16(o.x);
    p.b[1] = __float2bfloat16(o.y);
    p.b[2] = __float2bfloat16(o.z);
    p.b[3] = __float2bfloat16(o.w);
    *(ushort4*)((unsigned short*)xb + off) = p.u;
}

// ---------------------------------------------------------------------------
// Mean pool: 200 partial blocks + tiny finalize.
// ---------------------------------------------------------------------------
__global__ __launch_bounds__(256)
void pool_partial_kernel(const float* __restrict__ x, const int* __restrict__ batch,
                         float* __restrict__ sums) {
    int col = threadIdx.x & 63;
    int rl = threadIdx.x >> 6;
    int rs = blockIdx.x * 250;
    int re = rs + 250;
    int cur = -1;
    float acc = 0.f;
    for (int r = rs + rl; r < re; r += 4) {
        int g = batch[r];
        float v = x[(size_t)r * HD + col];
        if (g != cur) {
            if (cur >= 0) atomicAdd(&sums[cur * HD + col], acc);
            cur = g;
            acc = v;
        } else {
            acc += v;
        }
    }
    if (cur >= 0) atomicAdd(&sums[cur * HD + col], acc);
}

__device__ __forceinline__ int lower_bound_batch(const int* __restrict__ b, int val) {
    int lo = 0, hi = NN;
    while (lo < hi) {
        int mid = (lo + hi) >> 1;
        if (b[mid] < val) lo = mid + 1;
        else hi = mid;
    }
    return lo;
}

__global__ __launch_bounds__(1024)
void pool_finalize_kernel(const float* __restrict__ sums, const int* __restrict__ batch,
                          float* __restrict__ out) {
    int g = threadIdx.x >> 6;
    int col = threadIdx.x & 63;
    int s = lower_bound_batch(batch, g);
    int e = lower_bound_batch(batch, g + 1);
    float cnt = (float)(e - s);
    out[g * HD + col] = sums[g * HD + col] / fmaxf(cnt, 1.f);
}

extern "C" void kernel_launch(void* const* d_in, const int* in_sizes, int n_in,
                              void* d_out, int out_size, void* d_ws, size_t ws_size,
                              hipStream_t stream) {
    const float* x = (const float*)d_in[0];
    const int* ei = (const int*)d_in[1];
    const int* batch = (const int*)d_in[2];
    const float* W1_0 = (const float*)d_in[3];
    const float* b1_0 = (const float*)d_in[4];
    const float* W2_0 = (const float*)d_in[5];
    const float* b2_0 = (const float*)d_in[6];
    const float* g_0 = (const float*)d_in[7];
    const float* be_0 = (const float*)d_in[8];
    const float* W1_1 = (const float*)d_in[9];
    const float* b1_1 = (const float*)d_in[10];
    const float* W2_1 = (const float*)d_in[11];
    const float* b2_1 = (const float*)d_in[12];
    const float* g_1 = (const float*)d_in[13];
    const float* be_1 = (const float*)d_in[14];

    float* out = (float*)d_out;  // node output; also x1 staging between layers

    // workspace layout (~30 MB)
    float* buf_h = (float*)d_ws;                       // 3.2M f32 (agg output)
    float* stats = buf_h + (size_t)NN * HD;            // 128 f32
    float* psums = stats + 128;                        // 1024 f32
    int* row_ptr = (int*)(psums + 1024);               // NN+2
    int* cnt = row_ptr + (NN + 2);                     // NN
    int* partials = cnt + NN;                          // 256
    int* gcur = partials + 256;                        // 64
    int* csr = gcur + 64;                              // NE
    __hip_bfloat16* xb = (__hip_bfloat16*)(csr + NE);  // NN*HD bf16 (6.4MB)
    int2* part = (int2*)(xb + (size_t)NN * HD);        // NE int2 (6.4MB)

    dim3 b256(256);
    int mlp_grid = (NN + 127) / 128;       // 391
    int norm_grid = (NN * HD / 4 + 255) / 256;  // 3125
    int egrid = (NE + 255) / 256;          // 3125
    int agg_grid = NN / 4;                 // 12500

    // ---- x->bf16 table + cnt zeroing, then CSR build ----
    x2bf_kernel<<<norm_grid, b256, 0, stream>>>(x, xb, cnt);
    count_kernel<<<egrid, b256, 0, stream>>>(ei, cnt);
    scan1_kernel<<<SCAN_BLOCKS, b256, 0, stream>>>(cnt, row_ptr, partials);
    scan3_kernel<<<SCAN_BLOCKS, b256, 0, stream>>>(row_ptr, partials, gcur);
    bin1_kernel<<<BIN1_BLOCKS, b256, 0, stream>>>(ei, gcur, part);
    bin2_kernel<<<NBUCK, b256, 0, stream>>>(part, row_ptr, csr);

    // ---- layer 0 ----
    agg_kernel<<<agg_grid, b256, 0, stream>>>(x, xb, row_ptr, csr, buf_h, stats);
    mlp_kernel<<<mlp_grid, b256, 0, stream>>>(buf_h, out, W1_0, b1_0, W2_0, b2_0, stats, psums);
    norm_kernel<<<norm_grid, b256, 0, stream>>>(out, stats, g_0, be_0, xb);

    // ---- layer 1 ----
    agg_kernel<<<agg_grid, b256, 0, stream>>>(out, xb, row_ptr, csr, buf_h, stats);
    mlp_kernel<<<mlp_grid, b256, 0, stream>>>(buf_h, out, W1_1, b1_1, W2_1, b2_1, stats, psums);
    norm_kernel<<<norm_grid, b256, 0, stream>>>(out, stats, g_1, be_1, xb);

    // ---- pool ----
    pool_partial_kernel<<<200, b256, 0, stream>>>(out, batch, psums);
    pool_finalize_kernel<<<1, dim3(1024), 0, stream>>>(psums, batch, out + (size_t)NN * HD);
}